// Round 10
// baseline (643.452 us; speedup 1.0000x reference)
//
#include <hip/hip_runtime.h>
#include <hip/hip_bf16.h>

typedef __hip_bfloat16 bf16;

#define NEG_SLOPE 0.2f

__device__ __forceinline__ float b2f(bf16 v) { return __bfloat162float(v); }
__device__ __forceinline__ float lrelu(float x) { return x >= 0.f ? x : NEG_SLOPE * x; }
// packed bf16x2 (as uint) -> two floats
__device__ __forceinline__ float2 bf2x(unsigned pv) {
    float2 r;
    r.x = __uint_as_float(pv << 16);
    r.y = __uint_as_float(pv & 0xffff0000u);
    return r;
}

static inline int cdiv(int a, int b) { return (a + b - 1) / b; }

// ---------------- diagnostic fill (ws too small)
__global__ void fill_sentinel(float* __restrict__ y, int n) {
    int t = blockIdx.x * 256 + threadIdx.x;
    if (t < n) y[t] = 2.0f;
}

// ---------------- input assembly: x0 = concat(emb[node_ids], node_feats) [N,23] bf16
__global__ void build_x0(const int* __restrict__ ids, const float* __restrict__ feats,
                         const float* __restrict__ emb, bf16* __restrict__ x0, int N) {
    int t = blockIdx.x * 256 + threadIdx.x;
    if (t >= N * 23) return;
    int i = t / 23, j = t - i * 23;
    float v = (j < 8) ? emb[ids[i] * 8 + j] : feats[i * 15 + (j - 8)];
    x0[t] = __float2bfloat16(v);
}

// ---------------- CSR build (per call; no cross-call state allowed)
__global__ void csr_zero(int* __restrict__ counts, int N) {
    int t = blockIdx.x * 256 + threadIdx.x;
    if (t < N) counts[t] = 0;
}
__global__ void csr_count(const int* __restrict__ dst, int* __restrict__ counts, int E) {
    int t = blockIdx.x * 256 + threadIdx.x;
    if (t < E) atomicAdd(&counts[dst[t]], 1);
}
// 3-kernel parallel exclusive scan (N <= 262144: block sums fit one 1024-block)
__global__ void scan_blocksums(const int* __restrict__ counts, int* __restrict__ bsum, int N) {
    __shared__ int s[256];
    int i = blockIdx.x * 256 + threadIdx.x;
    s[threadIdx.x] = (i < N) ? counts[i] : 0;
    __syncthreads();
    for (int o = 128; o > 0; o >>= 1) {
        if (threadIdx.x < o) s[threadIdx.x] += s[threadIdx.x + o];
        __syncthreads();
    }
    if (threadIdx.x == 0) bsum[blockIdx.x] = s[0];
}
__global__ __launch_bounds__(1024) void scan_bsums(int* __restrict__ bsum, int nb) {
    __shared__ int part[1024];
    int t = threadIdx.x;
    int v = (t < nb) ? bsum[t] : 0;
    part[t] = v;
    __syncthreads();
    for (int o = 1; o < 1024; o <<= 1) {
        int u = (t >= o) ? part[t - o] : 0;
        __syncthreads();
        part[t] += u;
        __syncthreads();
    }
    if (t < nb) bsum[t] = part[t] - v;  // exclusive
}
__global__ void scan_final(const int* __restrict__ counts, const int* __restrict__ bsum,
                           int* __restrict__ off, int* __restrict__ cursor, int N) {
    __shared__ int s[256];
    int t = threadIdx.x;
    int i = blockIdx.x * 256 + t;
    int v = (i < N) ? counts[i] : 0;
    s[t] = v;
    __syncthreads();
    for (int o = 1; o < 256; o <<= 1) {
        int u = (t >= o) ? s[t - o] : 0;
        __syncthreads();
        s[t] += u;
        __syncthreads();
    }
    if (i < N) {
        int excl = s[t] - v + bsum[blockIdx.x];
        off[i] = excl;
        cursor[i] = excl;
        if (i == N - 1) off[N] = excl + v;
    }
}
// fallback fill (N > 65536): global-cursor scatter (write-amplified but general)
__global__ void csr_fill(const int* __restrict__ src, const int* __restrict__ dst,
                         int* __restrict__ cursor, int* __restrict__ elsrc, int E) {
    int t = blockIdx.x * 256 + threadIdx.x;
    if (t >= E) return;
    int slot = atomicAdd(&cursor[dst[t]], 1);
    elsrc[slot] = src[t];
}
// bucketed fill: block b owns dsts [256b,256b+256). Streams the edge list (L3-shared
// across blocks), keeps its bucket's edges in LDS, scatters into its PRIVATE contiguous
// elsrc region via LDS cursors -> no global atomics, no cross-XCD line thrash.
#define BCAP 16384  // 4x the 4080 mean edges/bucket for this graph; Poisson tail ~ 0
__global__ __launch_bounds__(1024) void bucket_fill(
    const int* __restrict__ src, const int* __restrict__ dst,
    const int* __restrict__ csr_off, int* __restrict__ elsrc, int N, int E) {
    __shared__ unsigned list[BCAP];
    __shared__ int lcur[256];
    __shared__ int lcnt;
    const int dlo = blockIdx.x * 256;
    const int dhi = min(dlo + 256, N);
    if (threadIdx.x == 0) lcnt = 0;
    if (threadIdx.x < 256) {
        int dd = dlo + threadIdx.x;
        lcur[threadIdx.x] = (dd < N) ? csr_off[dd] : 0;
    }
    __syncthreads();
    for (int i = threadIdx.x; i < E; i += 1024) {
        int d = dst[i];
        int s = src[i];
        if (d >= dlo && d < dhi) {
            int p = atomicAdd(&lcnt, 1);
            if (p < BCAP) list[p] = ((unsigned)(d - dlo) << 16) | (unsigned)s;
        }
    }
    __syncthreads();
    const int n = min(lcnt, BCAP);
    for (int p = threadIdx.x; p < n; p += 1024) {
        unsigned u = list[p];
        int slot = atomicAdd(&lcur[u >> 16], 1);
        elsrc[slot] = (int)(u & 0xffffu);
    }
}

// ---------------- per-node: h = x@W (bf16), alpha_s/alpha_d (f32)
template <int FIN, int H, int C>
__global__ __launch_bounds__(128) void node_transform(
    const bf16* __restrict__ x, const float* __restrict__ W,
    const float* __restrict__ av_s, const float* __restrict__ av_d,
    bf16* __restrict__ h_out, float* __restrict__ as_out, float* __restrict__ ad_out, int N) {
    constexpr int HC = H * C;
    constexpr int NB = 128 / HC;     // nodes per block
    constexpr int FINP = FIN + 4;    // 16B-aligned pad; breaks pow2-stride bank conflicts
    __shared__ float xs[NB * FINP];
    const int node0 = blockIdx.x * NB;
    const int tid = threadIdx.x;
    for (int idx = tid; idx < NB * FIN; idx += 128) {
        int ln = idx / FIN, f = idx - ln * FIN;
        int i = node0 + ln;
        xs[ln * FINP + f] = (i < N) ? b2f(x[(size_t)i * FIN + f]) : 0.f;
    }
    __syncthreads();
    const int ln = tid / HC, j = tid - ln * HC;
    const int i = node0 + ln;
    if (i >= N) return;
    float acc = 0.f;
    if constexpr ((FIN & 3) == 0) {
#pragma unroll
        for (int f = 0; f < FIN; f += 4) {
            float4 xv = *(const float4*)&xs[ln * FINP + f];
            acc += xv.x * W[(f + 0) * HC + j] + xv.y * W[(f + 1) * HC + j] +
                   xv.z * W[(f + 2) * HC + j] + xv.w * W[(f + 3) * HC + j];
        }
    } else {
#pragma unroll
        for (int f = 0; f < FIN; ++f) acc += xs[ln * FINP + f] * W[f * HC + j];
    }
    h_out[(size_t)i * HC + j] = __float2bfloat16(acc);
    float s = acc * av_s[j];
    float d = acc * av_d[j];
#pragma unroll
    for (int off = C / 2; off > 0; off >>= 1) {
        s += __shfl_down(s, off, C);
        d += __shfl_down(d, off, C);
    }
    if ((j & (C - 1)) == 0) {
        as_out[i * H + j / C] = s;
        ad_out[i * H + j / C] = d;
    }
}

// ---------------- fused per-dst GAT, shift-by-self-score softmax.
// One wave per dst; lane owns 8 channels (bf16x8 = 16B gathers); EPI edges in flight.
template <int H, int C, bool SIGMOID>
__global__ __launch_bounds__(256) void gat_aggregate(
    const int* __restrict__ csr_off, const int* __restrict__ elsrc,
    const bf16* __restrict__ hbuf, const float* __restrict__ asb,
    const float* __restrict__ adb, const float* __restrict__ bias,
    bf16* __restrict__ xout, float* __restrict__ yout, int N) {
    constexpr int HC = H * C;
    constexpr int LPR = HC / 8;      // lanes covering one h-row (bf16x8 each)
    constexpr int EPI = 64 / LPR;    // edges in flight per inner iteration
    __shared__ int src_s[4 * 64];
    __shared__ float w_s[4 * 64 * H];
    const int wvi = threadIdx.x >> 6;
    const int lane = threadIdx.x & 63;
    const int d = blockIdx.x * 4 + wvi;
    if (d >= N) return;
    const int grp = lane / LPR;        // edge group within iteration
    const int lin = lane - grp * LPR;  // lane within row
    const int ch0 = 8 * lin;           // my 8 channels
    const int h0 = ch0 / C;            // my channels' head
    const int row = csr_off[d], end = csr_off[d + 1];

    float ad_d[H], c[H], den_p[H];
#pragma unroll
    for (int h = 0; h < H; ++h) {
        ad_d[h] = adb[d * H + h];
        c[h] = lrelu(asb[d * H + h] + ad_d[h]);  // shift constant = self-loop score
        den_p[h] = 0.f;
    }
    // self-loop contribution: weight exp(c-c)=1 (groups summed at the end)
    float acc[8];
#pragma unroll
    for (int r = 0; r < 8; ++r) acc[r] = 0.f;
    if (grp == 0) {
        uint4 pv = *(const uint4*)(hbuf + (size_t)d * HC + ch0);
        float2 p0 = bf2x(pv.x), p1 = bf2x(pv.y), p2 = bf2x(pv.z), p3 = bf2x(pv.w);
        acc[0] = p0.x; acc[1] = p0.y; acc[2] = p1.x; acc[3] = p1.y;
        acc[4] = p2.x; acc[5] = p2.y; acc[6] = p3.x; acc[7] = p3.y;
    }

    for (int base = row; base < end; base += 64) {
        int e = base + lane;
        int s = (e < end) ? elsrc[e] : -1;
        if constexpr (H == 4) {
            float4 w4 = {0.f, 0.f, 0.f, 0.f};
            if (s >= 0) {
                float4 av = *(const float4*)(asb + s * 4);
                w4.x = __expf(lrelu(av.x + ad_d[0]) - c[0]);
                w4.y = __expf(lrelu(av.y + ad_d[1]) - c[1]);
                w4.z = __expf(lrelu(av.z + ad_d[2]) - c[2]);
                w4.w = __expf(lrelu(av.w + ad_d[3]) - c[3]);
                den_p[0] += w4.x;
                den_p[1] += w4.y;
                den_p[2] += w4.z;
                den_p[3] += w4.w;
            }
            *(float4*)&w_s[(wvi * 64 + lane) * 4] = w4;
        } else {
            float w0 = 0.f;
            if (s >= 0) {
                w0 = __expf(lrelu(asb[s] + ad_d[0]) - c[0]);
                den_p[0] += w0;
            }
            w_s[wvi * 64 + lane] = w0;
        }
        src_s[wvi * 64 + lane] = (s >= 0) ? s : 0;
        int nv = min(64, end - base);
#pragma unroll 4
        for (int k0 = 0; k0 < nv; k0 += EPI) {
            int k = k0 + grp;
            if (k < nv) {
                int sk = src_s[wvi * 64 + k];
                float w = w_s[(wvi * 64 + k) * H + h0];
                uint4 pv = *(const uint4*)(hbuf + (size_t)sk * HC + ch0);
                float2 p0 = bf2x(pv.x), p1 = bf2x(pv.y), p2 = bf2x(pv.z), p3 = bf2x(pv.w);
                acc[0] += w * p0.x; acc[1] += w * p0.y;
                acc[2] += w * p1.x; acc[3] += w * p1.y;
                acc[4] += w * p2.x; acc[5] += w * p2.y;
                acc[6] += w * p3.x; acc[7] += w * p3.y;
            }
        }
    }
    // denominator: one wave reduction per head (once per wave)
#pragma unroll
    for (int h = 0; h < H; ++h) {
        float v = den_p[h];
#pragma unroll
        for (int o = 32; o > 0; o >>= 1) v += __shfl_xor(v, o, 64);
        den_p[h] = v + 1.0f;  // + self term
    }
    // sum partial accumulators across edge groups
#pragma unroll
    for (int o = LPR; o < 64; o <<= 1) {
#pragma unroll
        for (int r = 0; r < 8; ++r) acc[r] += __shfl_xor(acc[r], o, 64);
    }
    if (grp == 0) {
        float inv = 1.f / (den_p[h0] + 1e-16f);
        float v[8];
#pragma unroll
        for (int r = 0; r < 8; ++r) v[r] = acc[r] * inv + bias[ch0 + r];
        if (SIGMOID) {
            float4 o0, o1;
            o0.x = 1.f / (1.f + __expf(-v[0]));
            o0.y = 1.f / (1.f + __expf(-v[1]));
            o0.z = 1.f / (1.f + __expf(-v[2]));
            o0.w = 1.f / (1.f + __expf(-v[3]));
            o1.x = 1.f / (1.f + __expf(-v[4]));
            o1.y = 1.f / (1.f + __expf(-v[5]));
            o1.z = 1.f / (1.f + __expf(-v[6]));
            o1.w = 1.f / (1.f + __expf(-v[7]));
            *(float4*)(yout + (size_t)d * HC + ch0) = o0;
            *(float4*)(yout + (size_t)d * HC + ch0 + 4) = o1;
        } else {
            union { ushort u[8]; uint4 p; } o;
#pragma unroll
            for (int r = 0; r < 8; ++r)
                o.u[r] = __bfloat16_as_ushort(__float2bfloat16(v[r] > 0.f ? v[r] : 0.f));
            *(uint4*)(xout + (size_t)d * HC + ch0) = o.p;
        }
    }
}

extern "C" void kernel_launch(void* const* d_in, const int* in_sizes, int n_in,
                              void* d_out, int out_size, void* d_ws, size_t ws_size,
                              hipStream_t stream) {
    const int N = in_sizes[0];
    const int E = in_sizes[2] / 2;
    const int* node_ids = (const int*)d_in[0];
    const float* feats = (const float*)d_in[1];
    const int* srcI = (const int*)d_in[2];
    const int* dstI = srcI + E;
    const float* emb = (const float*)d_in[4];
    const float* W1 = (const float*)d_in[5];
    const float* a1s = (const float*)d_in[6];
    const float* a1d = (const float*)d_in[7];
    const float* b1 = (const float*)d_in[8];
    const float* W2 = (const float*)d_in[9];
    const float* a2s = (const float*)d_in[10];
    const float* a2d = (const float*)d_in[11];
    const float* b2 = (const float*)d_in[12];
    const float* W3 = (const float*)d_in[13];
    const float* a3s = (const float*)d_in[14];
    const float* a3d = (const float*)d_in[15];
    const float* b3 = (const float*)d_in[16];
    const float* W4 = (const float*)d_in[17];
    const float* a4s = (const float*)d_in[18];
    const float* a4d = (const float*)d_in[19];
    const float* b4 = (const float*)d_in[20];
    float* y = (float*)d_out;

    const int nb = cdiv(N, 256);

    // workspace layout (~31 MB @ N=50000, E=800000)
    float* asb = (float*)d_ws;                       // N*4 f32
    float* adb = asb + (size_t)N * 4;                // N*4 f32
    bf16* xbuf = (bf16*)(adb + (size_t)N * 4);       // N*128 bf16
    bf16* hbuf = xbuf + (size_t)N * 128;             // N*128 bf16
    int* counts = (int*)(hbuf + (size_t)N * 128);    // N
    int* csr_off = counts + N;                       // N+1
    int* cursor = csr_off + N + 1;                   // N
    int* elsrc = cursor + N;                         // E
    int* bsum = elsrc + E;                           // nb (<=1024)

    size_t need = (size_t)N * 4 * 4 * 2 + (size_t)N * 128 * 2 * 2 +
                  ((size_t)3 * N + 1 + E + 1024) * 4;
    if (ws_size < need || nb > 1024) {
        fill_sentinel<<<cdiv(out_size, 256), 256, 0, stream>>>(y, out_size);
        return;
    }

    // CSR by dst (segment-internal edge order arbitrary -> only fp rounding differs)
    csr_zero<<<cdiv(N, 256), 256, 0, stream>>>(counts, N);
    csr_count<<<cdiv(E, 256), 256, 0, stream>>>(dstI, counts, E);
    scan_blocksums<<<nb, 256, 0, stream>>>(counts, bsum, N);
    scan_bsums<<<1, 1024, 0, stream>>>(bsum, nb);
    scan_final<<<nb, 256, 0, stream>>>(counts, bsum, csr_off, cursor, N);
    if (N <= 65536) {  // bucketed fill needs src to fit 16 bits
        bucket_fill<<<nb, 1024, 0, stream>>>(srcI, dstI, csr_off, elsrc, N, E);
    } else {
        csr_fill<<<cdiv(E, 256), 256, 0, stream>>>(srcI, dstI, cursor, elsrc, E);
    }

    build_x0<<<cdiv(N * 23, 256), 256, 0, stream>>>(node_ids, feats, emb, xbuf, N);

#define LAYER(FIN, H, C, WP, ASP, ADP, BP, SIG)                                           \
    node_transform<FIN, H, C><<<cdiv(N, 128 / (H * C)), 128, 0, stream>>>(                \
        xbuf, WP, ASP, ADP, hbuf, asb, adb, N);                                           \
    gat_aggregate<H, C, SIG><<<cdiv(N, 4), 256, 0, stream>>>(csr_off, elsrc, hbuf,        \
                                                             asb, adb, BP, xbuf, y, N);

    LAYER(23, 4, 32, W1, a1s, a1d, b1, false)    // 23 -> 4x32, relu
    LAYER(128, 1, 32, W2, a2s, a2d, b2, false)   // 128 -> 32, relu
    LAYER(32, 4, 32, W3, a3s, a3d, b3, false)    // 32 -> 4x32, relu
    LAYER(128, 1, 16, W4, a4s, a4d, b4, true)    // 128 -> 16, sigmoid -> f32 out

#undef LAYER
}

// Round 11
// 442.631 us; speedup vs baseline: 1.4537x; 1.4537x over previous
//
#include <hip/hip_runtime.h>
#include <hip/hip_bf16.h>

typedef __hip_bfloat16 bf16;

#define NEG_SLOPE 0.2f

__device__ __forceinline__ float b2f(bf16 v) { return __bfloat162float(v); }
__device__ __forceinline__ float lrelu(float x) { return x >= 0.f ? x : NEG_SLOPE * x; }
// packed bf16x2 (as uint) -> two floats
__device__ __forceinline__ float2 bf2x(unsigned pv) {
    float2 r;
    r.x = __uint_as_float(pv << 16);
    r.y = __uint_as_float(pv & 0xffff0000u);
    return r;
}

static inline int cdiv(int a, int b) { return (a + b - 1) / b; }

// ---------------- diagnostic fill (ws too small)
__global__ void fill_sentinel(float* __restrict__ y, int n) {
    int t = blockIdx.x * 256 + threadIdx.x;
    if (t < n) y[t] = 2.0f;
}

// ---------------- CSR build (per call; no cross-call state allowed)
__global__ void csr_zero(int* __restrict__ counts, int N) {
    int t = blockIdx.x * 256 + threadIdx.x;
    if (t < N) counts[t] = 0;
}
__global__ void csr_count(const int* __restrict__ dst, int* __restrict__ counts, int E) {
    int t = blockIdx.x * 256 + threadIdx.x;
    if (t < E) atomicAdd(&counts[dst[t]], 1);
}
// 3-kernel parallel exclusive scan (N <= 262144: block sums fit one 1024-block)
__global__ void scan_blocksums(const int* __restrict__ counts, int* __restrict__ bsum, int N) {
    __shared__ int s[256];
    int i = blockIdx.x * 256 + threadIdx.x;
    s[threadIdx.x] = (i < N) ? counts[i] : 0;
    __syncthreads();
    for (int o = 128; o > 0; o >>= 1) {
        if (threadIdx.x < o) s[threadIdx.x] += s[threadIdx.x + o];
        __syncthreads();
    }
    if (threadIdx.x == 0) bsum[blockIdx.x] = s[0];
}
__global__ __launch_bounds__(1024) void scan_bsums(int* __restrict__ bsum, int nb) {
    __shared__ int part[1024];
    int t = threadIdx.x;
    int v = (t < nb) ? bsum[t] : 0;
    part[t] = v;
    __syncthreads();
    for (int o = 1; o < 1024; o <<= 1) {
        int u = (t >= o) ? part[t - o] : 0;
        __syncthreads();
        part[t] += u;
        __syncthreads();
    }
    if (t < nb) bsum[t] = part[t] - v;  // exclusive
}
__global__ void scan_final(const int* __restrict__ counts, const int* __restrict__ bsum,
                           int* __restrict__ off, int* __restrict__ cursor, int N) {
    __shared__ int s[256];
    int t = threadIdx.x;
    int i = blockIdx.x * 256 + t;
    int v = (i < N) ? counts[i] : 0;
    s[t] = v;
    __syncthreads();
    for (int o = 1; o < 256; o <<= 1) {
        int u = (t >= o) ? s[t - o] : 0;
        __syncthreads();
        s[t] += u;
        __syncthreads();
    }
    if (i < N) {
        int excl = s[t] - v + bsum[blockIdx.x];
        off[i] = excl;
        cursor[i] = excl;
        if (i == N - 1) off[N] = excl + v;
    }
}
// scatter fill; ushort payload when src ids fit 16 bits (halves line-granular
// write amplification: 52 -> ~27 MB), int fallback otherwise.
__global__ void csr_fill_u16(const int* __restrict__ src, const int* __restrict__ dst,
                             int* __restrict__ cursor, ushort* __restrict__ elsrc, int E) {
    int t = blockIdx.x * 256 + threadIdx.x;
    if (t >= E) return;
    int slot = atomicAdd(&cursor[dst[t]], 1);
    elsrc[slot] = (ushort)src[t];
}
__global__ void csr_fill_i32(const int* __restrict__ src, const int* __restrict__ dst,
                             int* __restrict__ cursor, int* __restrict__ elsrc, int E) {
    int t = blockIdx.x * 256 + threadIdx.x;
    if (t >= E) return;
    int slot = atomicAdd(&cursor[dst[t]], 1);
    elsrc[slot] = src[t];
}

// ---------------- per-node: h = x@W (bf16), alpha_s/alpha_d (f32)
// FUSE: layer-1 variant builds x = concat(emb[ids], feats) inline (FIN==23).
template <int FIN, int H, int C, bool FUSE>
__global__ __launch_bounds__(128) void node_transform(
    const bf16* __restrict__ x, const int* __restrict__ ids,
    const float* __restrict__ feats, const float* __restrict__ emb,
    const float* __restrict__ W, const float* __restrict__ av_s,
    const float* __restrict__ av_d, bf16* __restrict__ h_out,
    float* __restrict__ as_out, float* __restrict__ ad_out, int N) {
    constexpr int HC = H * C;
    constexpr int NB = 128 / HC;     // nodes per block
    constexpr int FINP = FIN + 4;    // 16B-aligned pad; breaks pow2-stride bank conflicts
    __shared__ float xs[NB * FINP];
    const int node0 = blockIdx.x * NB;
    const int tid = threadIdx.x;
    for (int idx = tid; idx < NB * FIN; idx += 128) {
        int ln = idx / FIN, f = idx - ln * FIN;
        int i = node0 + ln;
        float v = 0.f;
        if (i < N) {
            if constexpr (FUSE)
                v = (f < 8) ? emb[ids[i] * 8 + f] : feats[i * 15 + (f - 8)];
            else
                v = b2f(x[(size_t)i * FIN + f]);
        }
        xs[ln * FINP + f] = v;
    }
    __syncthreads();
    const int ln = tid / HC, j = tid - ln * HC;
    const int i = node0 + ln;
    if (i >= N) return;
    float acc = 0.f;
    if constexpr ((FIN & 3) == 0) {
#pragma unroll
        for (int f = 0; f < FIN; f += 4) {
            float4 xv = *(const float4*)&xs[ln * FINP + f];
            acc += xv.x * W[(f + 0) * HC + j] + xv.y * W[(f + 1) * HC + j] +
                   xv.z * W[(f + 2) * HC + j] + xv.w * W[(f + 3) * HC + j];
        }
    } else {
#pragma unroll
        for (int f = 0; f < FIN; ++f) acc += xs[ln * FINP + f] * W[f * HC + j];
    }
    h_out[(size_t)i * HC + j] = __float2bfloat16(acc);
    float s = acc * av_s[j];
    float d = acc * av_d[j];
#pragma unroll
    for (int off = C / 2; off > 0; off >>= 1) {
        s += __shfl_down(s, off, C);
        d += __shfl_down(d, off, C);
    }
    if ((j & (C - 1)) == 0) {
        as_out[i * H + j / C] = s;
        ad_out[i * H + j / C] = d;
    }
}

// ---------------- fused per-dst GAT, shift-by-self-score softmax.
// One wave per dst; lane owns 8 channels (bf16x8 = 16B gathers); EPI edges in flight.
template <int H, int C, bool SIGMOID, typename EIDX>
__global__ __launch_bounds__(256) void gat_aggregate(
    const int* __restrict__ csr_off, const EIDX* __restrict__ elsrc,
    const bf16* __restrict__ hbuf, const float* __restrict__ asb,
    const float* __restrict__ adb, const float* __restrict__ bias,
    bf16* __restrict__ xout, float* __restrict__ yout, int N) {
    constexpr int HC = H * C;
    constexpr int LPR = HC / 8;      // lanes covering one h-row (bf16x8 each)
    constexpr int EPI = 64 / LPR;    // edges in flight per inner iteration
    __shared__ int src_s[4 * 64];
    __shared__ float w_s[4 * 64 * H];
    const int wvi = threadIdx.x >> 6;
    const int lane = threadIdx.x & 63;
    const int d = blockIdx.x * 4 + wvi;
    if (d >= N) return;
    const int grp = lane / LPR;        // edge group within iteration
    const int lin = lane - grp * LPR;  // lane within row
    const int ch0 = 8 * lin;           // my 8 channels
    const int h0 = ch0 / C;            // my channels' head
    const int row = csr_off[d], end = csr_off[d + 1];

    float ad_d[H], c[H], den_p[H];
#pragma unroll
    for (int h = 0; h < H; ++h) {
        ad_d[h] = adb[d * H + h];
        c[h] = lrelu(asb[d * H + h] + ad_d[h]);  // shift constant = self-loop score
        den_p[h] = 0.f;
    }
    // self-loop contribution: weight exp(c-c)=1 (groups summed at the end)
    float acc[8];
#pragma unroll
    for (int r = 0; r < 8; ++r) acc[r] = 0.f;
    if (grp == 0) {
        uint4 pv = *(const uint4*)(hbuf + (size_t)d * HC + ch0);
        float2 p0 = bf2x(pv.x), p1 = bf2x(pv.y), p2 = bf2x(pv.z), p3 = bf2x(pv.w);
        acc[0] = p0.x; acc[1] = p0.y; acc[2] = p1.x; acc[3] = p1.y;
        acc[4] = p2.x; acc[5] = p2.y; acc[6] = p3.x; acc[7] = p3.y;
    }

    for (int base = row; base < end; base += 64) {
        int e = base + lane;
        int s = (e < end) ? (int)elsrc[e] : -1;
        if constexpr (H == 4) {
            float4 w4 = {0.f, 0.f, 0.f, 0.f};
            if (s >= 0) {
                float4 av = *(const float4*)(asb + s * 4);
                w4.x = __expf(lrelu(av.x + ad_d[0]) - c[0]);
                w4.y = __expf(lrelu(av.y + ad_d[1]) - c[1]);
                w4.z = __expf(lrelu(av.z + ad_d[2]) - c[2]);
                w4.w = __expf(lrelu(av.w + ad_d[3]) - c[3]);
                den_p[0] += w4.x;
                den_p[1] += w4.y;
                den_p[2] += w4.z;
                den_p[3] += w4.w;
            }
            *(float4*)&w_s[(wvi * 64 + lane) * 4] = w4;
        } else {
            float w0 = 0.f;
            if (s >= 0) {
                w0 = __expf(lrelu(asb[s] + ad_d[0]) - c[0]);
                den_p[0] += w0;
            }
            w_s[wvi * 64 + lane] = w0;
        }
        src_s[wvi * 64 + lane] = (s >= 0) ? s : 0;
        int nv = min(64, end - base);
#pragma unroll 4
        for (int k0 = 0; k0 < nv; k0 += EPI) {
            int k = k0 + grp;
            if (k < nv) {
                int sk = src_s[wvi * 64 + k];
                float w = w_s[(wvi * 64 + k) * H + h0];
                uint4 pv = *(const uint4*)(hbuf + (size_t)sk * HC + ch0);
                float2 p0 = bf2x(pv.x), p1 = bf2x(pv.y), p2 = bf2x(pv.z), p3 = bf2x(pv.w);
                acc[0] += w * p0.x; acc[1] += w * p0.y;
                acc[2] += w * p1.x; acc[3] += w * p1.y;
                acc[4] += w * p2.x; acc[5] += w * p2.y;
                acc[6] += w * p3.x; acc[7] += w * p3.y;
            }
        }
    }
    // denominator: one wave reduction per head (once per wave)
#pragma unroll
    for (int h = 0; h < H; ++h) {
        float v = den_p[h];
#pragma unroll
        for (int o = 32; o > 0; o >>= 1) v += __shfl_xor(v, o, 64);
        den_p[h] = v + 1.0f;  // + self term
    }
    // sum partial accumulators across edge groups
#pragma unroll
    for (int o = LPR; o < 64; o <<= 1) {
#pragma unroll
        for (int r = 0; r < 8; ++r) acc[r] += __shfl_xor(acc[r], o, 64);
    }
    if (grp == 0) {
        float inv = 1.f / (den_p[h0] + 1e-16f);
        float v[8];
#pragma unroll
        for (int r = 0; r < 8; ++r) v[r] = acc[r] * inv + bias[ch0 + r];
        if (SIGMOID) {
            float4 o0, o1;
            o0.x = 1.f / (1.f + __expf(-v[0]));
            o0.y = 1.f / (1.f + __expf(-v[1]));
            o0.z = 1.f / (1.f + __expf(-v[2]));
            o0.w = 1.f / (1.f + __expf(-v[3]));
            o1.x = 1.f / (1.f + __expf(-v[4]));
            o1.y = 1.f / (1.f + __expf(-v[5]));
            o1.z = 1.f / (1.f + __expf(-v[6]));
            o1.w = 1.f / (1.f + __expf(-v[7]));
            *(float4*)(yout + (size_t)d * HC + ch0) = o0;
            *(float4*)(yout + (size_t)d * HC + ch0 + 4) = o1;
        } else {
            union { ushort u[8]; uint4 p; } o;
#pragma unroll
            for (int r = 0; r < 8; ++r)
                o.u[r] = __bfloat16_as_ushort(__float2bfloat16(v[r] > 0.f ? v[r] : 0.f));
            *(uint4*)(xout + (size_t)d * HC + ch0) = o.p;
        }
    }
}

// ---------------- the 4 GAT layers, templated on edge-index storage type
template <typename EIDX>
static void run_layers(const int* csr_off, const EIDX* elsrc, const int* node_ids,
                       const float* feats, const float* emb, bf16* xbuf, bf16* hbuf,
                       float* asb, float* adb, float* y, void* const* d_in, int N,
                       hipStream_t stream) {
    const float* W1 = (const float*)d_in[5];
    const float* a1s = (const float*)d_in[6];
    const float* a1d = (const float*)d_in[7];
    const float* b1 = (const float*)d_in[8];
    const float* W2 = (const float*)d_in[9];
    const float* a2s = (const float*)d_in[10];
    const float* a2d = (const float*)d_in[11];
    const float* b2 = (const float*)d_in[12];
    const float* W3 = (const float*)d_in[13];
    const float* a3s = (const float*)d_in[14];
    const float* a3d = (const float*)d_in[15];
    const float* b3 = (const float*)d_in[16];
    const float* W4 = (const float*)d_in[17];
    const float* a4s = (const float*)d_in[18];
    const float* a4d = (const float*)d_in[19];
    const float* b4 = (const float*)d_in[20];

#define LAYER(FIN, H, C, FUSE, WP, ASP, ADP, BP, SIG)                                      \
    node_transform<FIN, H, C, FUSE><<<cdiv(N, 128 / (H * C)), 128, 0, stream>>>(           \
        xbuf, node_ids, feats, emb, WP, ASP, ADP, hbuf, asb, adb, N);                      \
    gat_aggregate<H, C, SIG, EIDX><<<cdiv(N, 4), 256, 0, stream>>>(csr_off, elsrc, hbuf,   \
                                                                   asb, adb, BP, xbuf, y, N);

    LAYER(23, 4, 32, true, W1, a1s, a1d, b1, false)     // 23 -> 4x32, relu
    LAYER(128, 1, 32, false, W2, a2s, a2d, b2, false)   // 128 -> 32, relu
    LAYER(32, 4, 32, false, W3, a3s, a3d, b3, false)    // 32 -> 4x32, relu
    LAYER(128, 1, 16, false, W4, a4s, a4d, b4, true)    // 128 -> 16, sigmoid -> f32 out
#undef LAYER
}

extern "C" void kernel_launch(void* const* d_in, const int* in_sizes, int n_in,
                              void* d_out, int out_size, void* d_ws, size_t ws_size,
                              hipStream_t stream) {
    const int N = in_sizes[0];
    const int E = in_sizes[2] / 2;
    const int* node_ids = (const int*)d_in[0];
    const float* feats = (const float*)d_in[1];
    const int* srcI = (const int*)d_in[2];
    const int* dstI = srcI + E;
    const float* emb = (const float*)d_in[4];
    float* y = (float*)d_out;

    const int nb = cdiv(N, 256);

    // workspace layout (~31 MB @ N=50000, E=800000)
    float* asb = (float*)d_ws;                       // N*4 f32
    float* adb = asb + (size_t)N * 4;                // N*4 f32
    bf16* xbuf = (bf16*)(adb + (size_t)N * 4);       // N*128 bf16
    bf16* hbuf = xbuf + (size_t)N * 128;             // N*128 bf16
    int* counts = (int*)(hbuf + (size_t)N * 128);    // N
    int* csr_off = counts + N;                       // N+1
    int* cursor = csr_off + N + 1;                   // N
    int* elsrc = cursor + N;                         // E ints (or E ushorts)
    int* bsum = elsrc + E;                           // nb (<=1024)

    size_t need = (size_t)N * 4 * 4 * 2 + (size_t)N * 128 * 2 * 2 +
                  ((size_t)3 * N + 1 + E + 1024) * 4;
    if (ws_size < need || nb > 1024) {
        fill_sentinel<<<cdiv(out_size, 256), 256, 0, stream>>>(y, out_size);
        return;
    }

    // CSR by dst (segment-internal edge order arbitrary -> only fp rounding differs)
    csr_zero<<<cdiv(N, 256), 256, 0, stream>>>(counts, N);
    csr_count<<<cdiv(E, 256), 256, 0, stream>>>(dstI, counts, E);
    scan_blocksums<<<nb, 256, 0, stream>>>(counts, bsum, N);
    scan_bsums<<<1, 1024, 0, stream>>>(bsum, nb);
    scan_final<<<nb, 256, 0, stream>>>(counts, bsum, csr_off, cursor, N);

    if (N <= 65536) {  // src fits ushort -> halve scatter write amplification
        ushort* el16 = (ushort*)elsrc;
        csr_fill_u16<<<cdiv(E, 256), 256, 0, stream>>>(srcI, dstI, cursor, el16, E);
        run_layers<ushort>(csr_off, el16, node_ids, feats, emb, xbuf, hbuf, asb, adb, y,
                           d_in, N, stream);
    } else {
        csr_fill_i32<<<cdiv(E, 256), 256, 0, stream>>>(srcI, dstI, cursor, elsrc, E);
        run_layers<int>(csr_off, elsrc, node_ids, feats, emb, xbuf, hbuf, asb, adb, y,
                        d_in, N, stream);
    }
}